// Round 13
// baseline (85.341 us; speedup 1.0000x reference)
//
#include <hip/hip_runtime.h>

// Problem constants (match reference setup)
#define BB     4
#define NW     128
#define HG     512
#define WG     512
#define EDIM   64
#define HIDDEN 768
#define CTS    132

typedef float f4 __attribute__((ext_vector_type(4)));

// d_ws layout (bytes):
//   ctabT : [BB][EDIM][CTS] f32  @ 0   (135,168 B)
#define WS_CTABT  0

// ---------------------------------------------------------------------------
// Prep: 132 blocks -> ctabT[b][e][n] (LDS-tiled GEMM, verified R6 pattern).
// ---------------------------------------------------------------------------
__global__ __launch_bounds__(256) void prep_kernel(
    const float* __restrict__ emb,
    const float* __restrict__ proj,
    const int*   __restrict__ ids,
    float*       __restrict__ ctabT)
{
    const int t  = threadIdx.x;
    const int bx = blockIdx.x;

    __shared__ float proj_s[64][68];
    __shared__ float emb_s[4][68];

    const int b = bx / 33, ng = bx % 33;
    const int e = t & 63, r = t >> 6;
    const int n = ng * 4 + r;              // 0..131
    const bool valid = (n <= NW);
    const int id = (!valid || n == 0) ? 0 : ids[b * NW + n - 1];
    const float* erow = emb + (size_t)id * HIDDEN;

    float acc = 0.f;
    for (int kt = 0; kt < HIDDEN; kt += 64) {
        if (e < 16)
            *(f4*)&emb_s[r][e * 4] = ((const f4*)(erow + kt))[e];
        #pragma unroll
        for (int q = t; q < 1024; q += 256) {
            const int pr = q >> 4, pc = q & 15;
            *(f4*)&proj_s[pr][pc * 4] =
                ((const f4*)(proj + (size_t)pr * HIDDEN + kt))[pc];
        }
        __syncthreads();
        #pragma unroll
        for (int k4 = 0; k4 < 16; ++k4) {
            f4 a = *(const f4*)&emb_s[r][k4 * 4];
            f4 p = *(const f4*)&proj_s[e][k4 * 4];
            acc += a.x * p.x + a.y * p.y + a.z * p.z + a.w * p.w;
        }
        __syncthreads();
    }
    if (valid) ctabT[((size_t)(b * EDIM + e)) * CTS + n] = acc;
}

// ---------------------------------------------------------------------------
// Paint: R10 structure VERBATIM except phase 2 reads col values from L2 ctab
// instead of computing 768-dots. 1024 blocks = 8 XCDs x 128 (bijective
// swizzle); TWO e-planes per block, 64-row tile, 4 waves x 16 rows.
// Plain f4 stores (NT bypasses L2 write-combining: R8 = -10.5 us).
// ---------------------------------------------------------------------------
__global__ __launch_bounds__(256) void paint_kernel(
    const float* __restrict__ bbox,
    const int*   __restrict__ stride_p,
    const float* __restrict__ ctabT,
    float*       __restrict__ out)
{
    const int t = threadIdx.x;
    // 1024 = 8 XCDs x 128; block i -> XCD i%8 -> contiguous lin chunk.
    const int lin = ((blockIdx.x & 7) << 7) | (blockIdx.x >> 3);
    const int b  = lin >> 8;             // 2 XCDs per batch
    const int e0 = ((lin >> 3) & 31) * 2;
    const int ht = lin & 7;
    const int rlo = ht * 64, rhi = rlo + 64;

    __shared__ unsigned entx[NW];        // w0 | w1<<10 | prio<<20
    __shared__ unsigned enty[NW];        // h0 | h1<<16
    __shared__ float    col0[NW + 1];    // plane e0 values by prio (0=bg)
    __shared__ float    col1[NW + 1];    // plane e0+1
    __shared__ unsigned char sublist[8][NW];
    __shared__ int      subcnt[8];
    __shared__ int      cnt;

    if (t == 0) cnt = 0;
    if (t < 8)  subcnt[t] = 0;
    __syncthreads();

    // ---- Phase 1: box filter for this 64-row tile ----
    if (t < NW) {
        const float s = (float)stride_p[0];
        float4 bv = ((const float4*)bbox)[b * NW + t];
        int w0 = (int)rintf(bv.x / s), h0 = (int)rintf(bv.y / s);
        int w1 = (int)rintf(bv.z / s), h1 = (int)rintf(bv.w / s);
        if (h1 > rlo && h0 < rhi && w1 > w0 && h1 > h0) {
            int i = atomicAdd(&cnt, 1);
            entx[i] = (unsigned)w0 | ((unsigned)w1 << 10) | ((unsigned)(t + 1) << 20);
            enty[i] = (unsigned)h0 | ((unsigned)h1 << 16);
        }
    }
    __syncthreads();

    const int nc = cnt;
    const int wv = t >> 6, l = t & 63;

    // ---- Phase 1b: bucket entries into per-8-row sub-tile lists ----
    if (t < nc) {
        const unsigned ey = enty[t];
        const int h0 = (int)(ey & 0xFFFFu), h1 = (int)(ey >> 16);
        #pragma unroll
        for (int st = 0; st < 8; ++st) {
            const int srl = rlo + st * 8;
            if (h1 > srl && h0 < srl + 8) {
                int k = atomicAdd(&subcnt[st], 1);
                sublist[st][k] = (unsigned char)t;
            }
        }
    }

    // ---- Phase 2: fetch needed col values from L2 ctab (~38 scalars) ----
    for (int idx = t; idx < (nc + 1) * 2; idx += 256) {
        const int j = idx >> 1, p = idx & 1;
        const int slot = (j == nc) ? 0 : (int)(entx[j] >> 20);
        const float v = ctabT[((size_t)(b * EDIM + e0 + p)) * CTS + slot];
        if (p == 0) col0[slot] = v;
        else        col1[slot] = v;
    }
    __syncthreads();

    // ---- Phase 3: paint 16 rows per wave; winner once, both planes ----
    float* obase0 = out + ((size_t)(b * EDIM + e0)) * HG * WG;
    float* obase1 = obase0 + (size_t)HG * WG;
    const int p0 = 4 * l, p1 = 256 + 4 * l;

    const float bgs0 = col0[0], bgs1 = col1[0];
    const f4 bgv0 = {bgs0, bgs0, bgs0, bgs0};
    const f4 bgv1 = {bgs1, bgs1, bgs1, bgs1};

    for (int rr = 0; rr < 16; ++rr) {
        const int ro  = wv * 16 + rr;
        const int row = rlo + ro;                     // wave-uniform
        const int st  = ro >> 3;
        const int ns  = subcnt[st];
        f4* orow0 = (f4*)(obase0 + (size_t)row * WG);
        f4* orow1 = (f4*)(obase1 + (size_t)row * WG);

        if (ns == 0) {                                // bg fast path
            orow0[l]      = bgv0;
            orow0[64 + l] = bgv0;
            orow1[l]      = bgv1;
            orow1[64 + l] = bgv1;
            continue;
        }

        int wn0 = 0, wn1 = 0, wn2 = 0, wn3 = 0;
        int wn4 = 0, wn5 = 0, wn6 = 0, wn7 = 0;
        for (int k = 0; k < ns; ++k) {
            const int i = sublist[st][k];
            const unsigned ey = enty[i];               // broadcast LDS read
            const int h0 = (int)(ey & 0xFFFFu), h1 = (int)(ey >> 16);
            if (row >= h0 && row < h1) {               // wave-uniform branch
                const unsigned ex = entx[i];
                const int w0 = (int)(ex & 1023u);
                const int w1 = (int)((ex >> 10) & 1023u);
                const int pr = (int)(ex >> 20);
                if (p0     >= w0 && p0     < w1 && pr > wn0) wn0 = pr;
                if (p0 + 1 >= w0 && p0 + 1 < w1 && pr > wn1) wn1 = pr;
                if (p0 + 2 >= w0 && p0 + 2 < w1 && pr > wn2) wn2 = pr;
                if (p0 + 3 >= w0 && p0 + 3 < w1 && pr > wn3) wn3 = pr;
                if (p1     >= w0 && p1     < w1 && pr > wn4) wn4 = pr;
                if (p1 + 1 >= w0 && p1 + 1 < w1 && pr > wn5) wn5 = pr;
                if (p1 + 2 >= w0 && p1 + 2 < w1 && pr > wn6) wn6 = pr;
                if (p1 + 3 >= w0 && p1 + 3 < w1 && pr > wn7) wn7 = pr;
            }
        }
        f4 u0, u1, w0v, w1v;
        u0.x  = col0[wn0]; u0.y  = col0[wn1]; u0.z  = col0[wn2]; u0.w  = col0[wn3];
        u1.x  = col0[wn4]; u1.y  = col0[wn5]; u1.z  = col0[wn6]; u1.w  = col0[wn7];
        w0v.x = col1[wn0]; w0v.y = col1[wn1]; w0v.z = col1[wn2]; w0v.w = col1[wn3];
        w1v.x = col1[wn4]; w1v.y = col1[wn5]; w1v.z = col1[wn6]; w1v.w = col1[wn7];
        orow0[l]      = u0;
        orow0[64 + l] = u1;
        orow1[l]      = w0v;
        orow1[64 + l] = w1v;
    }
}

// ---------------------------------------------------------------------------
extern "C" void kernel_launch(void* const* d_in, const int* in_sizes, int n_in,
                              void* d_out, int out_size, void* d_ws, size_t ws_size,
                              hipStream_t stream)
{
    // inputs: 0 img (unused), 1 bbox, 2 emb_weight, 3 proj_weight,
    //         4 input_ids, 5 stride
    const float* bbox = (const float*)d_in[1];
    const float* emb  = (const float*)d_in[2];
    const float* proj = (const float*)d_in[3];
    const int*   ids  = (const int*)d_in[4];
    const int*   strd = (const int*)d_in[5];

    float* out = (float*)d_out;
    char*  ws  = (char*)d_ws;
    float* ctabT = (float*)(ws + WS_CTABT);

    prep_kernel<<<132, 256, 0, stream>>>(emb, proj, ids, ctabT);

    paint_kernel<<<1024, 256, 0, stream>>>(bbox, strd, ctabT, out);
}

// Round 14
// 56.509 us; speedup vs baseline: 1.5102x; 1.5102x over previous
//
#include <hip/hip_runtime.h>

// Problem constants (match reference setup)
#define BB     4
#define NW     128
#define HG     512
#define WG     512
#define EDIM   64
#define HIDDEN 768

typedef float f4 __attribute__((ext_vector_type(4)));

// ---------------------------------------------------------------------------
// Single fused kernel — R10 structure with DOUBLED OCCUPANCY.
// 2048 blocks = 8 XCDs x 256; lin = b(2)|e5(5)|ht(4); 2 e-planes per block,
// 32-row tile, wave = one 8-row sub-tile. 8 blocks/CU -> 32 waves/CU.
// Plain f4 stores (NT bypasses L2 write-combining: R8 = -10.5 us).
//
// Phase 1 : filter this batch's 128 boxes against rows [ht*32, ht*32+32).
// Phase 1b: bucket filtered entries into 4 per-8-row sub-tile lists.
// Phase 2 : wave-parallel 768-dots for both planes; emb row loaded once.
// Phase 3 : per-row winner-max once, gather BOTH planes via same indices.
// ---------------------------------------------------------------------------
__global__ __launch_bounds__(256) void fused_kernel(
    const float* __restrict__ bbox,
    const float* __restrict__ emb,
    const float* __restrict__ proj,
    const int*   __restrict__ ids,
    const int*   __restrict__ stride_p,
    float*       __restrict__ out)
{
    const int t = threadIdx.x;
    // 2048 = 8 XCDs x 256; block i -> XCD i%8 -> contiguous lin chunk.
    const int lin = ((blockIdx.x & 7) << 8) | (blockIdx.x >> 3);
    const int b  = lin >> 9;             // 2 XCDs per batch
    const int e0 = ((lin >> 4) & 31) * 2;
    const int ht = lin & 15;
    const int rlo = ht * 32, rhi = rlo + 32;

    __shared__ unsigned entx[NW];        // w0 | w1<<10 | prio<<20
    __shared__ unsigned enty[NW];        // h0 | h1<<16
    __shared__ int      sid[NW];         // word id per filtered box
    __shared__ float    col0[NW + 1];    // plane e0 values by prio (0=bg)
    __shared__ float    col1[NW + 1];    // plane e0+1
    __shared__ unsigned char sublist[4][NW];
    __shared__ int      subcnt[4];
    __shared__ int      cnt;

    if (t == 0) cnt = 0;
    if (t < 4)  subcnt[t] = 0;
    __syncthreads();

    // ---- Phase 1: box filter for this 32-row tile ----
    if (t < NW) {
        const float s = (float)stride_p[0];
        float4 bv = ((const float4*)bbox)[b * NW + t];
        int w0 = (int)rintf(bv.x / s), h0 = (int)rintf(bv.y / s);
        int w1 = (int)rintf(bv.z / s), h1 = (int)rintf(bv.w / s);
        if (h1 > rlo && h0 < rhi && w1 > w0 && h1 > h0) {
            int i = atomicAdd(&cnt, 1);
            entx[i] = (unsigned)w0 | ((unsigned)w1 << 10) | ((unsigned)(t + 1) << 20);
            enty[i] = (unsigned)h0 | ((unsigned)h1 << 16);
            sid[i]  = ids[b * NW + t];
        }
    }
    __syncthreads();

    const int nc = cnt;
    const int wv = t >> 6, l = t & 63;

    // ---- Phase 1b: bucket entries into per-8-row sub-tile lists ----
    if (t < nc) {
        const unsigned ey = enty[t];
        const int h0 = (int)(ey & 0xFFFFu), h1 = (int)(ey >> 16);
        #pragma unroll
        for (int st = 0; st < 4; ++st) {
            const int srl = rlo + st * 8;
            if (h1 > srl && h0 < srl + 8) {
                int k = atomicAdd(&subcnt[st], 1);
                sublist[st][k] = (unsigned char)t;
            }
        }
    }

    // ---- Phase 2: table entries for BOTH planes (j == nc -> background) ----
    const f4* prbase0 = (const f4*)(proj + (size_t)e0 * HIDDEN) + l * 3;
    const f4* prbase1 = (const f4*)(proj + (size_t)(e0 + 1) * HIDDEN) + l * 3;
    f4 q00 = prbase0[0], q01 = prbase0[1], q02 = prbase0[2];
    f4 q10 = prbase1[0], q11 = prbase1[1], q12 = prbase1[2];

    for (int j = wv; j <= nc; j += 4) {
        const int id   = (j == nc) ? 0 : sid[j];
        const int slot = (j == nc) ? 0 : (int)(entx[j] >> 20);
        const f4* er = (const f4*)(emb + (size_t)id * HIDDEN) + l * 3;
        f4 a0 = er[0], a1 = er[1], a2 = er[2];
        float v0 = a0.x*q00.x + a0.y*q00.y + a0.z*q00.z + a0.w*q00.w
                 + a1.x*q01.x + a1.y*q01.y + a1.z*q01.z + a1.w*q01.w
                 + a2.x*q02.x + a2.y*q02.y + a2.z*q02.z + a2.w*q02.w;
        float v1 = a0.x*q10.x + a0.y*q10.y + a0.z*q10.z + a0.w*q10.w
                 + a1.x*q11.x + a1.y*q11.y + a1.z*q11.z + a1.w*q11.w
                 + a2.x*q12.x + a2.y*q12.y + a2.z*q12.z + a2.w*q12.w;
        #pragma unroll
        for (int m = 1; m < 64; m <<= 1) {
            v0 += __shfl_xor(v0, m, 64);
            v1 += __shfl_xor(v1, m, 64);
        }
        if (l == 0) { col0[slot] = v0; col1[slot] = v1; }
    }
    __syncthreads();

    // ---- Phase 3: paint 8 rows per wave; winner once, both planes ----
    float* obase0 = out + ((size_t)(b * EDIM + e0)) * HG * WG;
    float* obase1 = obase0 + (size_t)HG * WG;
    const int p0 = 4 * l, p1 = 256 + 4 * l;

    const float bgs0 = col0[0], bgs1 = col1[0];
    const f4 bgv0 = {bgs0, bgs0, bgs0, bgs0};
    const f4 bgv1 = {bgs1, bgs1, bgs1, bgs1};

    const int ns = subcnt[wv];                        // wave = one sub-tile
    for (int rr = 0; rr < 8; ++rr) {
        const int row = rlo + wv * 8 + rr;            // wave-uniform
        f4* orow0 = (f4*)(obase0 + (size_t)row * WG);
        f4* orow1 = (f4*)(obase1 + (size_t)row * WG);

        if (ns == 0) {                                // bg fast path
            orow0[l]      = bgv0;
            orow0[64 + l] = bgv0;
            orow1[l]      = bgv1;
            orow1[64 + l] = bgv1;
            continue;
        }

        int wn0 = 0, wn1 = 0, wn2 = 0, wn3 = 0;
        int wn4 = 0, wn5 = 0, wn6 = 0, wn7 = 0;
        for (int k = 0; k < ns; ++k) {
            const int i = sublist[wv][k];
            const unsigned ey = enty[i];               // broadcast LDS read
            const int h0 = (int)(ey & 0xFFFFu), h1 = (int)(ey >> 16);
            if (row >= h0 && row < h1) {               // wave-uniform branch
                const unsigned ex = entx[i];
                const int w0 = (int)(ex & 1023u);
                const int w1 = (int)((ex >> 10) & 1023u);
                const int pr = (int)(ex >> 20);
                if (p0     >= w0 && p0     < w1 && pr > wn0) wn0 = pr;
                if (p0 + 1 >= w0 && p0 + 1 < w1 && pr > wn1) wn1 = pr;
                if (p0 + 2 >= w0 && p0 + 2 < w1 && pr > wn2) wn2 = pr;
                if (p0 + 3 >= w0 && p0 + 3 < w1 && pr > wn3) wn3 = pr;
                if (p1     >= w0 && p1     < w1 && pr > wn4) wn4 = pr;
                if (p1 + 1 >= w0 && p1 + 1 < w1 && pr > wn5) wn5 = pr;
                if (p1 + 2 >= w0 && p1 + 2 < w1 && pr > wn6) wn6 = pr;
                if (p1 + 3 >= w0 && p1 + 3 < w1 && pr > wn7) wn7 = pr;
            }
        }
        f4 u0, u1, w0v, w1v;
        u0.x  = col0[wn0]; u0.y  = col0[wn1]; u0.z  = col0[wn2]; u0.w  = col0[wn3];
        u1.x  = col0[wn4]; u1.y  = col0[wn5]; u1.z  = col0[wn6]; u1.w  = col0[wn7];
        w0v.x = col1[wn0]; w0v.y = col1[wn1]; w0v.z = col1[wn2]; w0v.w = col1[wn3];
        w1v.x = col1[wn4]; w1v.y = col1[wn5]; w1v.z = col1[wn6]; w1v.w = col1[wn7];
        orow0[l]      = u0;
        orow0[64 + l] = u1;
        orow1[l]      = w0v;
        orow1[64 + l] = w1v;
    }
}

// ---------------------------------------------------------------------------
extern "C" void kernel_launch(void* const* d_in, const int* in_sizes, int n_in,
                              void* d_out, int out_size, void* d_ws, size_t ws_size,
                              hipStream_t stream)
{
    // inputs: 0 img (unused), 1 bbox, 2 emb_weight, 3 proj_weight,
    //         4 input_ids, 5 stride
    const float* bbox = (const float*)d_in[1];
    const float* emb  = (const float*)d_in[2];
    const float* proj = (const float*)d_in[3];
    const int*   ids  = (const int*)d_in[4];
    const int*   strd = (const int*)d_in[5];

    float* out = (float*)d_out;

    fused_kernel<<<2048, 256, 0, stream>>>(bbox, emb, proj, ids, strd, out);
}